// Round 8
// baseline (89.471 us; speedup 1.0000x reference)
//
#include <hip/hip_runtime.h>

typedef __bf16 bf16_t;
typedef __attribute__((ext_vector_type(8))) __bf16 bf16x8;
typedef __attribute__((ext_vector_type(16))) float f32x16;
typedef __attribute__((ext_vector_type(8))) int i32x8;
typedef long long i64;
typedef __attribute__((ext_vector_type(2))) long long i64x2;
typedef unsigned long long u64;

#define MFMA32(A, B, C) __builtin_amdgcn_mfma_f32_32x32x16_bf16((A), (B), (C), 0, 0, 0)

// Problem constants: B=8, C=128, H=W=64 -> N=4096, R=16

__device__ __forceinline__ float fexp2(float x) { return __builtin_amdgcn_exp2f(x); }

// pack 4 f32 -> 4 fp8(e4m3) bytes
__device__ __forceinline__ unsigned pk4(float a, float b, float c, float d) {
  unsigned u = __builtin_amdgcn_cvt_pk_fp8_f32(a, b, 0u, false);
  return __builtin_amdgcn_cvt_pk_fp8_f32(c, d, u, true);
}
// exchange hi-half of a with lo-half of b (v_permlane32_swap)
__device__ __forceinline__ void swap32(unsigned &a, unsigned &b) {
  asm volatile("v_permlane32_swap_b32 %0, %1" : "+v"(a), "+v"(b));
}
// value of x in partner lane (lane ^ 32)
__device__ __forceinline__ float xhalf(float x, int hi) {
  unsigned a = __builtin_bit_cast(unsigned, x), b = a;
  asm volatile("v_permlane32_swap_b32 %0, %1" : "+v"(a), "+v"(b));
  return __builtin_bit_cast(float, hi ? a : b);
}
__device__ __forceinline__ unsigned pkbf2(float a, float b) {
  union { bf16_t h[2]; unsigned u; } r;
  r.h[0] = (bf16_t)a; r.h[1] = (bf16_t)b;
  return r.u;
}

// -------- kernel 1: fused transpose + q,kT,V-fp8 projections (64-n tiles) --------
// also casts Wo f32 -> bf16 (Wob) for the fused output GEMM.
// q[b][n][r]=QS*(Wq x+bq) (log2-domain); kT[b][m][r]=Wk x+bk;
// vf fp8, K=64 A-operand tiled, SPLIT-PLANE (R7-verified):
//   chunk(mq,sp,ct) = 2KB at b*524288 + mq*131072 + sp*8192 + ct*2048
//   plane0 (bytes 0-1023):    lane r's FIRST 16B of A-operand at r*16
//   plane1 (bytes 1024-2047): lane r's SECOND 16B at 1024 + r*16
//   (lane r = rhi*32+c31 holds V[c=ct*32+c31][m = mq*1024+sp*64+rhi*32 + 0..31])
__global__ __launch_bounds__(256) void k_qkv(
    const float* __restrict__ x,
    const float* __restrict__ Wq, const float* __restrict__ bq,
    const float* __restrict__ Wk, const float* __restrict__ bk,
    const float* __restrict__ Wv, const float* __restrict__ bv,
    const float* __restrict__ Wo,
    bf16_t* __restrict__ q, bf16_t* __restrict__ kT, char* __restrict__ vfout,
    bf16_t* __restrict__ Wob) {
  __shared__ __align__(16) bf16_t xt[64 * 136];      // [n_loc][c] bf16, stride 272B
  __shared__ __align__(16) bf16_t Wqk_s[32 * 136];
  __shared__ __align__(16) bf16_t Wv_s[128 * 152];   // stride 304B
  __shared__ __align__(8)  char   vst[128 * 72];     // fp8 stage [c][m_loc(64)+8pad]
  const float QS = 0.25f * 1.44269504f;  // scale * log2(e)
  const int b = blockIdx.y;
  const int nb = blockIdx.x;             // 64-col tile
  const int n0 = nb * 64;
  const int t = threadIdx.x;
  if (b == 0) {                          // Wo cast: 64 blocks x 256 = 16384 elems
    int i = nb * 256 + t;
    Wob[i] = (bf16_t)Wo[i];
  }
  for (int i = t; i < 32 * 128; i += 256) {
    int row = i >> 7, col = i & 127;
    float val = (row < 16) ? QS * Wq[row * 128 + col] : Wk[(row - 16) * 128 + col];
    Wqk_s[row * 136 + col] = (bf16_t)val;
  }
  for (int i = t; i < 128 * 128; i += 256)
    Wv_s[(i >> 7) * 152 + (i & 127)] = (bf16_t)Wv[i];

  // ---- one-pass transpose stage: x[c][n] f32 -> xt[n][c] bf16 ----
  const int nl = t & 63, cg = t >> 6;    // thread: n=nl, c-quarter cg
  const float* xb = x + (size_t)b * 524288 + n0 + nl;
  float xv[32];
#pragma unroll
  for (int i = 0; i < 32; ++i) xv[i] = xb[(size_t)(cg * 32 + i) * 4096];
  char* xrow = (char*)xt + nl * 272 + cg * 64;
#pragma unroll
  for (int i = 0; i < 16; ++i)
    *(unsigned*)(xrow + 4 * i) = pkbf2(xv[2 * i], xv[2 * i + 1]);
  __syncthreads();

  const int w = t >> 6, l = t & 63, l31 = l & 31, hi = l >> 5;
  const int nc = w & 1, role = w >> 1;   // waves: 2 n-chunks x 2 roles
  const int nloc = nc * 32 + l31;

  f32x16 aqk;
  f32x16 av[2];
#pragma unroll
  for (int i = 0; i < 16; ++i) { aqk[i] = 0.f; av[0][i] = 0.f; av[1][i] = 0.f; }
#pragma unroll
  for (int kk = 0; kk < 8; ++kk) {
    bf16x8 xf = *(const bf16x8*)((char*)xt + nloc * 272 + kk * 32 + hi * 16);
    if (role == 0) {
      bf16x8 wqk = *(const bf16x8*)(&Wqk_s[l31 * 136 + kk * 16 + 8 * hi]);
      aqk = MFMA32(xf, wqk, aqk);   // D[n][col]: col<16 -> q, col>=16 -> k
    }
#pragma unroll
    for (int j = 0; j < 2; ++j) {
      int ct = role * 2 + j;
      bf16x8 wvv = *(const bf16x8*)(&Wv_s[(ct * 32 + l31) * 152 + kk * 16 + 8 * hi]);
      av[j] = MFMA32(wvv, xf, av[j]);  // D[c_out][n]
    }
  }
  if (role == 0) {
    const float bias_qk = (l31 < 16) ? QS * bq[l31] : bk[l31 - 16];
#pragma unroll
    for (int r = 0; r < 16; ++r) {
      int n = n0 + nc * 32 + (r & 3) + 8 * (r >> 2) + 4 * hi;
      bf16_t vb16 = (bf16_t)(aqk[r] + bias_qk);
      if (l31 < 16) q[((size_t)(b * 4096 + n)) * 16 + l31] = vb16;
      else          kT[((size_t)(b * 4096 + n)) * 16 + (l31 - 16)] = vb16;
    }
  }

  // ---- v epilogue: fp8 convert -> vst[c][m_loc] ----
  const int mloc = nc * 32 + l31;
#pragma unroll
  for (int j = 0; j < 2; ++j) {
    int ct = role * 2 + j;
#pragma unroll
    for (int r = 0; r < 16; r += 2) {
      int c = ct * 32 + (r & 3) + 8 * (r >> 2) + 4 * hi;
      unsigned pw = pk4(av[j][r] + bv[c], av[j][r + 1] + bv[c + 1], 0.f, 0.f);
      vst[c * 72 + mloc] = (char)(pw & 0xff);
      vst[(c + 1) * 72 + mloc] = (char)((pw >> 8) & 0xff);
    }
  }
  __syncthreads();
  // ---- K=64 A-operand writeout, SPLIT-PLANE. Block covers exactly one sp (64 m).
  // thread t: ct = t>>6, r = t&63 (= MFMA lane), rhi = r>>5 (k-half), c31 = r&31.
  {
    char* vfb = vfout + (size_t)b * 524288 + (size_t)(nb >> 4) * 131072 + (size_t)(nb & 15) * 8192;
    const int ct = t >> 6, r = t & 63, rhi = r >> 5, c31 = r & 31;
    const char* src = vst + (ct * 32 + c31) * 72 + rhi * 32;
    u64 d0 = *(const u64*)(src);
    u64 d1 = *(const u64*)(src + 8);
    u64 d2 = *(const u64*)(src + 16);
    u64 d3 = *(const u64*)(src + 24);
    u64* dst0 = (u64*)(vfb + (size_t)ct * 2048 + (size_t)r * 16);
    u64* dst1 = (u64*)(vfb + (size_t)ct * 2048 + 1024 + (size_t)r * 16);
    dst0[0] = d0; dst0[1] = d1;
    dst1[0] = d2; dst1[1] = d3;
  }
}

// -------- kernel 2: flash attention + fused Wo epilogue --------
// 512 blocks = 8 batch x 64 q-blocks(64q). 8 waves = 2 q-chunks x 4 m-quarters.
// R8 synthesis of 8 rounds of evidence:
//  - K=64 scaled-MFMA PV kept (verified R5-R7; matrix cyc/sp = 1168 vs R0 2430).
//  - Barriers, LDS V-ring, staging DELETED: R7 showed the per-sp barrier lockstep
//    + staging + drain cost ~2000 cyc/sp of stall (53% issue-sat vs R0's 73%);
//    conflicts were never critical-path (R7: conflicts -5.6x, dur flat).
//  - V read GLOBAL-DIRECT from the split-plane layout (16B/lane coalesced
//    planes), ua/ub 2-live rotate (16 VGPR, the budget R6 proved fits).
//  - Softmax reverted to exp2+cvt_pk_fp8 (R0 form): R3's "fast exp" was a net
//    VALU INCREASE (40 -> 110 instrs, VALUBusy 38->47 measured); also restores
//    true e4m3 rounding (absmax back to ~0.015625).
__global__ __launch_bounds__(512, 4) void k_attn(
    const bf16_t* __restrict__ q, const bf16_t* __restrict__ kT,
    const char* __restrict__ vf, const bf16_t* __restrict__ Wob,
    const float* __restrict__ bo, const float* __restrict__ gammap,
    const float* __restrict__ x, float* __restrict__ out) {
  __shared__ __align__(16) bf16_t accb[8][32][136];  // 69.6 KB (epilogue only)
  __shared__ float lsum[8][32];
  __shared__ float linv[64];
  const int bid = blockIdx.x;
  const int b = bid & 7, qb = bid >> 3;   // batch-in-low-bits -> XCD/L2 affinity
  const int t = threadIdx.x, w = t >> 6, l = t & 63, l31 = l & 31, hi = l >> 5;
  const int qg = w & 1, mq = w >> 1;
  const int n0 = qb * 64 + qg * 32;

  const bf16_t* kw = kT + (size_t)b * 65536 + (size_t)mq * 16384;
  // per-wave V base (split-plane): chunk = vw + sp*8192 + ct*2048; +0 / +1024 planes
  const char* vw = vf + (size_t)b * 524288 + (size_t)mq * 131072 + (size_t)l * 16;

  bf16x8 qf = *(const bf16x8*)(q + ((size_t)(b * 4096) + n0 + l31) * 16 + 8 * hi);
  bf16x8 kf0 = *(const bf16x8*)(kw + (size_t)l31 * 16 + 8 * hi);
  bf16x8 kf1 = *(const bf16x8*)(kw + (size_t)(32 + l31) * 16 + 8 * hi);

  f32x16 z;
#pragma unroll
  for (int i = 0; i < 16; ++i) z[i] = 0.f;
  f32x16 acc[4];
#pragma unroll
  for (int ct = 0; ct < 4; ++ct) acc[ct] = z;
  float lac = 0.f;

  // prologue: ct0 of sp0 in flight
  union u32x8u { i64x2 p[2]; i32x8 v; };
  u32x8u ua, ub;
  ua.p[0] = *(const i64x2*)(vw);
  ua.p[1] = *(const i64x2*)(vw + 1024);

#pragma unroll 1
  for (int sp = 0; sp < 16; ++sp) {      // 16 step-pairs (64 m each)
    const size_t spo = (size_t)sp * 8192;
    // ct1 in flight; lands during QK/pack phase (~500 cyc of cover)
    ub.p[0] = *(const i64x2*)(vw + spo + 2048);
    ub.p[1] = *(const i64x2*)(vw + spo + 2048 + 1024);

    // ---- QK + softmax-pack, st0 then st1 serialized (register pressure) ----
    unsigned w0s, w1s, w2s, w3s, w0t, w1t, w2t, w3t;
    {
      f32x16 st0 = MFMA32(kf0, qf, z);   // D[m][n]: m=(r&3)+8(r>>2)+4hi (rows sp*64+0..31)
      if (sp < 15) kf0 = *(const bf16x8*)(kw + ((size_t)((sp + 1) * 64 + l31)) * 16 + 8 * hi);
      float p[16];
#pragma unroll
      for (int i = 0; i < 16; ++i) p[i] = fexp2(st0[i]);
      float s0 = (p[0] + p[1]) + (p[2] + p[3]), s1 = (p[4] + p[5]) + (p[6] + p[7]);
      float s2 = (p[8] + p[9]) + (p[10] + p[11]), s3 = (p[12] + p[13]) + (p[14] + p[15]);
      lac += (s0 + s1) + (s2 + s3);
      w0s = pk4(p[0], p[1], p[2], p[3]);
      w1s = pk4(p[4], p[5], p[6], p[7]);
      w2s = pk4(p[8], p[9], p[10], p[11]);
      w3s = pk4(p[12], p[13], p[14], p[15]);
    }
    {
      f32x16 st1 = MFMA32(kf1, qf, z);   // rows sp*64+32..63
      if (sp < 15) kf1 = *(const bf16x8*)(kw + ((size_t)((sp + 1) * 64 + 32 + l31)) * 16 + 8 * hi);
      float p[16];
#pragma unroll
      for (int i = 0; i < 16; ++i) p[i] = fexp2(st1[i]);
      float s0 = (p[0] + p[1]) + (p[2] + p[3]), s1 = (p[4] + p[5]) + (p[6] + p[7]);
      float s2 = (p[8] + p[9]) + (p[10] + p[11]), s3 = (p[12] + p[13]) + (p[14] + p[15]);
      lac += (s0 + s1) + (s2 + s3);
      w0t = pk4(p[0], p[1], p[2], p[3]);
      w1t = pk4(p[4], p[5], p[6], p[7]);
      w2t = pk4(p[8], p[9], p[10], p[11]);
      w3t = pk4(p[12], p[13], p[14], p[15]);
    }

    // pair-swaps (R5-verified): reg 2i = {hi0: st0 m-set_i, hi1: st1 m-set_i}
    swap32(w0s, w0t);
    swap32(w1s, w1t);
    swap32(w2s, w2t);
    swap32(w3s, w3t);
    i32x8 Bop;
    Bop[0] = (int)w0s; Bop[1] = (int)w0t;
    Bop[2] = (int)w1s; Bop[3] = (int)w1t;
    Bop[4] = (int)w2s; Bop[5] = (int)w2t;
    Bop[6] = (int)w3s; Bop[7] = (int)w3t;

    // ---- PV: 4 scaled K=64 MFMAs; ua/ub rotate keeps 2 chunks live (16 VGPR) ----
    const size_t nspo = (sp < 15) ? spo + 8192 : spo;   // clamp: sp15 reload (unused)
    acc[0] = __builtin_amdgcn_mfma_scale_f32_32x32x64_f8f6f4(
        ua.v, Bop, acc[0], 0, 0, 0, 0x7f7f7f7f, 0, 0x7f7f7f7f);
    ua.p[0] = *(const i64x2*)(vw + spo + 4096);          // ct2
    ua.p[1] = *(const i64x2*)(vw + spo + 4096 + 1024);
    acc[1] = __builtin_amdgcn_mfma_scale_f32_32x32x64_f8f6f4(
        ub.v, Bop, acc[1], 0, 0, 0, 0x7f7f7f7f, 0, 0x7f7f7f7f);
    ub.p[0] = *(const i64x2*)(vw + spo + 6144);          // ct3
    ub.p[1] = *(const i64x2*)(vw + spo + 6144 + 1024);
    acc[2] = __builtin_amdgcn_mfma_scale_f32_32x32x64_f8f6f4(
        ua.v, Bop, acc[2], 0, 0, 0, 0x7f7f7f7f, 0, 0x7f7f7f7f);
    ua.p[0] = *(const i64x2*)(vw + nspo);                // next sp ct0
    ua.p[1] = *(const i64x2*)(vw + nspo + 1024);
    acc[3] = __builtin_amdgcn_mfma_scale_f32_32x32x64_f8f6f4(
        ub.v, Bop, acc[3], 0, 0, 0, 0x7f7f7f7f, 0, 0x7f7f7f7f);
  }

  // ---- cross-mq combine (sum of partials) ----
  float lT = lac + xhalf(lac, hi);
  if (hi == 0) lsum[w][l31] = lT;
#pragma unroll
  for (int ct = 0; ct < 4; ++ct) {
#pragma unroll
    for (int g = 0; g < 4; ++g) {
      union { unsigned short h[4]; u64 u; } pw;
#pragma unroll
      for (int j = 0; j < 4; ++j) {
        bf16_t bb = (bf16_t)acc[ct][g * 4 + j];
        pw.h[j] = __builtin_bit_cast(unsigned short, bb);
      }
      *(u64*)&accb[w][l31][ct * 32 + 8 * g + 4 * hi] = pw.u;
    }
  }
  __syncthreads();

  {
    const int rn64 = t >> 3;            // 0..63 : local n
    const int qg2 = rn64 >> 5, rn = rn64 & 31;
    const int c0 = (t & 7) * 16;
    float L = (lsum[qg2][rn] + lsum[qg2 + 2][rn]) + (lsum[qg2 + 4][rn] + lsum[qg2 + 6][rn]);
    if ((t & 7) == 0) linv[rn64] = 1.0f / L;
    float o[16];
#pragma unroll
    for (int i = 0; i < 16; ++i) o[i] = 0.f;
#pragma unroll
    for (int m2 = 0; m2 < 4; ++m2) {
#pragma unroll
      for (int h2 = 0; h2 < 2; ++h2) {
        bf16x8 ch = *(const bf16x8*)&accb[qg2 + 2 * m2][rn][c0 + h2 * 8];
#pragma unroll
        for (int e = 0; e < 8; ++e) o[h2 * 8 + e] += (float)ch[e];
      }
    }
    // write combined RAW (unnormalized) back into accb[qg2][rn][c0..c0+15]
#pragma unroll
    for (int h2 = 0; h2 < 2; ++h2) {
      bf16x8 sv;
#pragma unroll
      for (int e = 0; e < 8; ++e) sv[e] = (bf16_t)o[h2 * 8 + e];
      *(bf16x8*)&accb[qg2][rn][c0 + h2 * 8] = sv;
    }
  }
  __syncthreads();

  // ---- fused output projection: out = gamma*(Wo @ attn + bo) + x ----
  // out is stream-once -> NT store (no L2 allocate); x load stays cached.
  {
    const int obk = w >> 1, nh = w & 1;
    const int o0 = obk * 32;
    f32x16 oc;
#pragma unroll
    for (int i = 0; i < 16; ++i) oc[i] = 0.f;
#pragma unroll
    for (int kk = 0; kk < 8; ++kk) {
      bf16x8 wof = *(const bf16x8*)(Wob + (size_t)(o0 + l31) * 128 + kk * 16 + 8 * hi);
      bf16x8 cf = *(const bf16x8*)&accb[nh][l31][kk * 16 + 8 * hi];
      oc = MFMA32(wof, cf, oc);  // D[o][n], n = l31
    }
    const float g = gammap[0];
    const float iv = linv[nh * 32 + l31];
    const int ng = qb * 64 + nh * 32 + l31;
#pragma unroll
    for (int r = 0; r < 16; ++r) {
      int o_ = o0 + (r & 3) + 8 * (r >> 2) + 4 * hi;
      size_t off = ((size_t)(b * 128 + o_)) * 4096 + ng;
      __builtin_nontemporal_store(g * (oc[r] * iv + bo[o_]) + x[off], &out[off]);
    }
  }
}

extern "C" void kernel_launch(void* const* d_in, const int* in_sizes, int n_in,
                              void* d_out, int out_size, void* d_ws, size_t ws_size,
                              hipStream_t stream) {
  const float* x  = (const float*)d_in[0];
  const float* Wq = (const float*)d_in[1];
  const float* bq = (const float*)d_in[2];
  const float* Wk = (const float*)d_in[3];
  const float* bk = (const float*)d_in[4];
  const float* Wv = (const float*)d_in[5];
  const float* bv = (const float*)d_in[6];
  const float* Wo = (const float*)d_in[7];
  const float* bo = (const float*)d_in[8];
  const float* gm = (const float*)d_in[9];
  float* out = (float*)d_out;

  char* ws = (char*)d_ws;
  bf16_t* q   = (bf16_t*)(ws);                        // 1 MB [B][N][16]
  bf16_t* kT  = (bf16_t*)(ws + (size_t)(1 << 20));    // 1 MB [B][N][16]
  char*   vf  = (char*)  (ws + (size_t)(2 << 20));    // 4 MB fp8 K=64-tiled V (split-plane)
  bf16_t* Wob = (bf16_t*)(ws + (size_t)(6 << 20));    // 32 KB Wo bf16

  k_qkv<<<dim3(64, 8), 256, 0, stream>>>(x, Wq, bq, Wk, bk, Wv, bv, Wo, q, kT, vf, Wob);
  k_attn<<<512, 512, 0, stream>>>(q, kT, vf, Wob, bo, gm, x, out);
}

// Round 9
// 63.318 us; speedup vs baseline: 1.4130x; 1.4130x over previous
//
#include <hip/hip_runtime.h>

typedef __bf16 bf16_t;
typedef __attribute__((ext_vector_type(8))) __bf16 bf16x8;
typedef __attribute__((ext_vector_type(16))) float f32x16;
typedef __attribute__((ext_vector_type(8))) int i32x8;
typedef long long i64;
typedef __attribute__((ext_vector_type(2))) long long i64x2;
typedef unsigned long long u64;

#define MFMA32(A, B, C) __builtin_amdgcn_mfma_f32_32x32x16_bf16((A), (B), (C), 0, 0, 0)

// Problem constants: B=8, C=128, H=W=64 -> N=4096, R=16

__device__ __forceinline__ float fexp2(float x) { return __builtin_amdgcn_exp2f(x); }

// pack 4 f32 -> 4 fp8(e4m3) bytes
__device__ __forceinline__ unsigned pk4(float a, float b, float c, float d) {
  unsigned u = __builtin_amdgcn_cvt_pk_fp8_f32(a, b, 0u, false);
  return __builtin_amdgcn_cvt_pk_fp8_f32(c, d, u, true);
}
// exchange hi-half of a with lo-half of b (v_permlane32_swap)
__device__ __forceinline__ void swap32(unsigned &a, unsigned &b) {
  asm volatile("v_permlane32_swap_b32 %0, %1" : "+v"(a), "+v"(b));
}
// value of x in partner lane (lane ^ 32)
__device__ __forceinline__ float xhalf(float x, int hi) {
  unsigned a = __builtin_bit_cast(unsigned, x), b = a;
  asm volatile("v_permlane32_swap_b32 %0, %1" : "+v"(a), "+v"(b));
  return __builtin_bit_cast(float, hi ? a : b);
}
__device__ __forceinline__ unsigned pkbf2(float a, float b) {
  union { bf16_t h[2]; unsigned u; } r;
  r.h[0] = (bf16_t)a; r.h[1] = (bf16_t)b;
  return r.u;
}

// -------- kernel 1: fused transpose + q,kT,V-fp8 projections (64-n tiles) --------
// also casts Wo f32 -> bf16 (Wob) for the fused output GEMM.
// q[b][n][r]=QS*(Wq x+bq) (log2-domain); kT[b][m][r]=Wk x+bk;
// vf fp8, K=64 A-operand tiled, SPLIT-PLANE (R7-verified):
//   chunk(mq,sp,ct) = 2KB at b*524288 + mq*131072 + sp*8192 + ct*2048
//   plane0 (bytes 0-1023):    lane r's FIRST 16B of A-operand at r*16
//   plane1 (bytes 1024-2047): lane r's SECOND 16B at 1024 + r*16
//   (lane r = rhi*32+c31 holds V[c=ct*32+c31][m = mq*1024+sp*64+rhi*32 + 0..31])
__global__ __launch_bounds__(256) void k_qkv(
    const float* __restrict__ x,
    const float* __restrict__ Wq, const float* __restrict__ bq,
    const float* __restrict__ Wk, const float* __restrict__ bk,
    const float* __restrict__ Wv, const float* __restrict__ bv,
    const float* __restrict__ Wo,
    bf16_t* __restrict__ q, bf16_t* __restrict__ kT, char* __restrict__ vfout,
    bf16_t* __restrict__ Wob) {
  __shared__ __align__(16) bf16_t xt[64 * 136];      // [n_loc][c] bf16, stride 272B
  __shared__ __align__(16) bf16_t Wqk_s[32 * 136];
  __shared__ __align__(16) bf16_t Wv_s[128 * 152];   // stride 304B
  __shared__ __align__(8)  char   vst[128 * 72];     // fp8 stage [c][m_loc(64)+8pad]
  const float QS = 0.25f * 1.44269504f;  // scale * log2(e)
  const int b = blockIdx.y;
  const int nb = blockIdx.x;             // 64-col tile
  const int n0 = nb * 64;
  const int t = threadIdx.x;
  if (b == 0) {                          // Wo cast: 64 blocks x 256 = 16384 elems
    int i = nb * 256 + t;
    Wob[i] = (bf16_t)Wo[i];
  }
  for (int i = t; i < 32 * 128; i += 256) {
    int row = i >> 7, col = i & 127;
    float val = (row < 16) ? QS * Wq[row * 128 + col] : Wk[(row - 16) * 128 + col];
    Wqk_s[row * 136 + col] = (bf16_t)val;
  }
  for (int i = t; i < 128 * 128; i += 256)
    Wv_s[(i >> 7) * 152 + (i & 127)] = (bf16_t)Wv[i];

  // ---- one-pass transpose stage: x[c][n] f32 -> xt[n][c] bf16 ----
  const int nl = t & 63, cg = t >> 6;    // thread: n=nl, c-quarter cg
  const float* xb = x + (size_t)b * 524288 + n0 + nl;
  float xv[32];
#pragma unroll
  for (int i = 0; i < 32; ++i) xv[i] = xb[(size_t)(cg * 32 + i) * 4096];
  char* xrow = (char*)xt + nl * 272 + cg * 64;
#pragma unroll
  for (int i = 0; i < 16; ++i)
    *(unsigned*)(xrow + 4 * i) = pkbf2(xv[2 * i], xv[2 * i + 1]);
  __syncthreads();

  const int w = t >> 6, l = t & 63, l31 = l & 31, hi = l >> 5;
  const int nc = w & 1, role = w >> 1;   // waves: 2 n-chunks x 2 roles
  const int nloc = nc * 32 + l31;

  f32x16 aqk;
  f32x16 av[2];
#pragma unroll
  for (int i = 0; i < 16; ++i) { aqk[i] = 0.f; av[0][i] = 0.f; av[1][i] = 0.f; }
#pragma unroll
  for (int kk = 0; kk < 8; ++kk) {
    bf16x8 xf = *(const bf16x8*)((char*)xt + nloc * 272 + kk * 32 + hi * 16);
    if (role == 0) {
      bf16x8 wqk = *(const bf16x8*)(&Wqk_s[l31 * 136 + kk * 16 + 8 * hi]);
      aqk = MFMA32(xf, wqk, aqk);   // D[n][col]: col<16 -> q, col>=16 -> k
    }
#pragma unroll
    for (int j = 0; j < 2; ++j) {
      int ct = role * 2 + j;
      bf16x8 wvv = *(const bf16x8*)(&Wv_s[(ct * 32 + l31) * 152 + kk * 16 + 8 * hi]);
      av[j] = MFMA32(wvv, xf, av[j]);  // D[c_out][n]
    }
  }
  if (role == 0) {
    const float bias_qk = (l31 < 16) ? QS * bq[l31] : bk[l31 - 16];
#pragma unroll
    for (int r = 0; r < 16; ++r) {
      int n = n0 + nc * 32 + (r & 3) + 8 * (r >> 2) + 4 * hi;
      bf16_t vb16 = (bf16_t)(aqk[r] + bias_qk);
      if (l31 < 16) q[((size_t)(b * 4096 + n)) * 16 + l31] = vb16;
      else          kT[((size_t)(b * 4096 + n)) * 16 + (l31 - 16)] = vb16;
    }
  }

  // ---- v epilogue: fp8 convert -> vst[c][m_loc] ----
  const int mloc = nc * 32 + l31;
#pragma unroll
  for (int j = 0; j < 2; ++j) {
    int ct = role * 2 + j;
#pragma unroll
    for (int r = 0; r < 16; r += 2) {
      int c = ct * 32 + (r & 3) + 8 * (r >> 2) + 4 * hi;
      unsigned pw = pk4(av[j][r] + bv[c], av[j][r + 1] + bv[c + 1], 0.f, 0.f);
      vst[c * 72 + mloc] = (char)(pw & 0xff);
      vst[(c + 1) * 72 + mloc] = (char)((pw >> 8) & 0xff);
    }
  }
  __syncthreads();
  // ---- K=64 A-operand writeout, SPLIT-PLANE. Block covers exactly one sp (64 m).
  // thread t: ct = t>>6, r = t&63 (= MFMA lane), rhi = r>>5 (k-half), c31 = r&31.
  {
    char* vfb = vfout + (size_t)b * 524288 + (size_t)(nb >> 4) * 131072 + (size_t)(nb & 15) * 8192;
    const int ct = t >> 6, r = t & 63, rhi = r >> 5, c31 = r & 31;
    const char* src = vst + (ct * 32 + c31) * 72 + rhi * 32;
    u64 d0 = *(const u64*)(src);
    u64 d1 = *(const u64*)(src + 8);
    u64 d2 = *(const u64*)(src + 16);
    u64 d3 = *(const u64*)(src + 24);
    u64* dst0 = (u64*)(vfb + (size_t)ct * 2048 + (size_t)r * 16);
    u64* dst1 = (u64*)(vfb + (size_t)ct * 2048 + 1024 + (size_t)r * 16);
    dst0[0] = d0; dst0[1] = d1;
    dst1[0] = d2; dst1[1] = d3;
  }
}

// -------- kernel 2: flash attention + fused Wo epilogue --------
// 512 blocks = 8 batch x 64 q-blocks(64q). 8 waves = 2 q-chunks x 4 m-quarters.
// R9 = R8 with PHASE-LOCAL live ranges (R8's spill signature: WRITE 17->46MB,
// FETCH flat => marginal scratch spill from live-range, not state size):
//  - NO load crosses the loop back-edge: ua(ct0)+ub(ct1) at loop top (latency
//    covered by QK+softmax ~800cy); ct2/ct3 issued mid-PV.
//  - kf single-rotate: kf1 loaded after QK0 (covered by softmax0); next-sp kf0
//    after QK1 (covered by softmax1). No body-long prefetch liveness.
//  - K=64 scaled-MFMA PV (verified R5-R8), split-plane coalesced V (R7),
//    exp2+pk4 softmax (R0/R8-verified numerics, absmax 0.015625).
__global__ __launch_bounds__(512, 4) void k_attn(
    const bf16_t* __restrict__ q, const bf16_t* __restrict__ kT,
    const char* __restrict__ vf, const bf16_t* __restrict__ Wob,
    const float* __restrict__ bo, const float* __restrict__ gammap,
    const float* __restrict__ x, float* __restrict__ out) {
  __shared__ __align__(16) bf16_t accb[8][32][136];  // 69.6 KB (epilogue only)
  __shared__ float lsum[8][32];
  __shared__ float linv[64];
  const int bid = blockIdx.x;
  const int b = bid & 7, qb = bid >> 3;   // batch-in-low-bits -> XCD/L2 affinity
  const int t = threadIdx.x, w = t >> 6, l = t & 63, l31 = l & 31, hi = l >> 5;
  const int qg = w & 1, mq = w >> 1;
  const int n0 = qb * 64 + qg * 32;

  const bf16_t* kw = kT + (size_t)b * 65536 + (size_t)mq * 16384;
  // per-wave V base (split-plane): chunk = vw + sp*8192 + ct*2048; +0 / +1024 planes
  const char* vw = vf + (size_t)b * 524288 + (size_t)mq * 131072 + (size_t)l * 16;

  bf16x8 qf = *(const bf16x8*)(q + ((size_t)(b * 4096) + n0 + l31) * 16 + 8 * hi);
  bf16x8 kf = *(const bf16x8*)(kw + (size_t)l31 * 16 + 8 * hi);   // sp0 kf0

  f32x16 z;
#pragma unroll
  for (int i = 0; i < 16; ++i) z[i] = 0.f;
  f32x16 acc[4];
#pragma unroll
  for (int ct = 0; ct < 4; ++ct) acc[ct] = z;
  float lac = 0.f;

  union u32x8u { i64x2 p[2]; i32x8 v; };

#pragma unroll 1
  for (int sp = 0; sp < 16; ++sp) {      // 16 step-pairs (64 m each)
    const char* vt = vw + (size_t)sp * 8192;
    // ct0+ct1 in flight; land during QK/softmax (~800 cyc of cover)
    u32x8u ua, ub;
    ua.p[0] = *(const i64x2*)(vt);
    ua.p[1] = *(const i64x2*)(vt + 1024);
    ub.p[0] = *(const i64x2*)(vt + 2048);
    ub.p[1] = *(const i64x2*)(vt + 2048 + 1024);

    // ---- QK + softmax-pack, st0 then st1 serialized; kf single-rotate ----
    unsigned w0s, w1s, w2s, w3s, w0t, w1t, w2t, w3t;
    {
      f32x16 st0 = MFMA32(kf, qf, z);    // D[m][n]: m=(r&3)+8(r>>2)+4hi (rows sp*64+0..31)
      kf = *(const bf16x8*)(kw + ((size_t)(sp * 64 + 32 + l31)) * 16 + 8 * hi);  // kf1
      float p[16];
#pragma unroll
      for (int i = 0; i < 16; ++i) p[i] = fexp2(st0[i]);
      float s0 = (p[0] + p[1]) + (p[2] + p[3]), s1 = (p[4] + p[5]) + (p[6] + p[7]);
      float s2 = (p[8] + p[9]) + (p[10] + p[11]), s3 = (p[12] + p[13]) + (p[14] + p[15]);
      lac += (s0 + s1) + (s2 + s3);
      w0s = pk4(p[0], p[1], p[2], p[3]);
      w1s = pk4(p[4], p[5], p[6], p[7]);
      w2s = pk4(p[8], p[9], p[10], p[11]);
      w3s = pk4(p[12], p[13], p[14], p[15]);
    }
    {
      f32x16 st1 = MFMA32(kf, qf, z);    // rows sp*64+32..63
      if (sp < 15)
        kf = *(const bf16x8*)(kw + ((size_t)((sp + 1) * 64 + l31)) * 16 + 8 * hi);  // next kf0
      float p[16];
#pragma unroll
      for (int i = 0; i < 16; ++i) p[i] = fexp2(st1[i]);
      float s0 = (p[0] + p[1]) + (p[2] + p[3]), s1 = (p[4] + p[5]) + (p[6] + p[7]);
      float s2 = (p[8] + p[9]) + (p[10] + p[11]), s3 = (p[12] + p[13]) + (p[14] + p[15]);
      lac += (s0 + s1) + (s2 + s3);
      w0t = pk4(p[0], p[1], p[2], p[3]);
      w1t = pk4(p[4], p[5], p[6], p[7]);
      w2t = pk4(p[8], p[9], p[10], p[11]);
      w3t = pk4(p[12], p[13], p[14], p[15]);
    }

    // pair-swaps (R5-verified): reg 2i = {hi0: st0 m-set_i, hi1: st1 m-set_i}
    swap32(w0s, w0t);
    swap32(w1s, w1t);
    swap32(w2s, w2t);
    swap32(w3s, w3t);
    i32x8 Bop;
    Bop[0] = (int)w0s; Bop[1] = (int)w0t;
    Bop[2] = (int)w1s; Bop[3] = (int)w1t;
    Bop[4] = (int)w2s; Bop[5] = (int)w2t;
    Bop[6] = (int)w3s; Bop[7] = (int)w3t;

    // ---- PV: 4 scaled K=64 MFMAs; ct2/ct3 issued mid-PV, consumed same phase ----
    acc[0] = __builtin_amdgcn_mfma_scale_f32_32x32x64_f8f6f4(
        ua.v, Bop, acc[0], 0, 0, 0, 0x7f7f7f7f, 0, 0x7f7f7f7f);
    ua.p[0] = *(const i64x2*)(vt + 4096);          // ct2
    ua.p[1] = *(const i64x2*)(vt + 4096 + 1024);
    acc[1] = __builtin_amdgcn_mfma_scale_f32_32x32x64_f8f6f4(
        ub.v, Bop, acc[1], 0, 0, 0, 0x7f7f7f7f, 0, 0x7f7f7f7f);
    ub.p[0] = *(const i64x2*)(vt + 6144);          // ct3
    ub.p[1] = *(const i64x2*)(vt + 6144 + 1024);
    acc[2] = __builtin_amdgcn_mfma_scale_f32_32x32x64_f8f6f4(
        ua.v, Bop, acc[2], 0, 0, 0, 0x7f7f7f7f, 0, 0x7f7f7f7f);
    acc[3] = __builtin_amdgcn_mfma_scale_f32_32x32x64_f8f6f4(
        ub.v, Bop, acc[3], 0, 0, 0, 0x7f7f7f7f, 0, 0x7f7f7f7f);
  }

  // ---- cross-mq combine (sum of partials) ----
  float lT = lac + xhalf(lac, hi);
  if (hi == 0) lsum[w][l31] = lT;
#pragma unroll
  for (int ct = 0; ct < 4; ++ct) {
#pragma unroll
    for (int g = 0; g < 4; ++g) {
      union { unsigned short h[4]; u64 u; } pw;
#pragma unroll
      for (int j = 0; j < 4; ++j) {
        bf16_t bb = (bf16_t)acc[ct][g * 4 + j];
        pw.h[j] = __builtin_bit_cast(unsigned short, bb);
      }
      *(u64*)&accb[w][l31][ct * 32 + 8 * g + 4 * hi] = pw.u;
    }
  }
  __syncthreads();

  {
    const int rn64 = t >> 3;            // 0..63 : local n
    const int qg2 = rn64 >> 5, rn = rn64 & 31;
    const int c0 = (t & 7) * 16;
    float L = (lsum[qg2][rn] + lsum[qg2 + 2][rn]) + (lsum[qg2 + 4][rn] + lsum[qg2 + 6][rn]);
    if ((t & 7) == 0) linv[rn64] = 1.0f / L;
    float o[16];
#pragma unroll
    for (int i = 0; i < 16; ++i) o[i] = 0.f;
#pragma unroll
    for (int m2 = 0; m2 < 4; ++m2) {
#pragma unroll
      for (int h2 = 0; h2 < 2; ++h2) {
        bf16x8 ch = *(const bf16x8*)&accb[qg2 + 2 * m2][rn][c0 + h2 * 8];
#pragma unroll
        for (int e = 0; e < 8; ++e) o[h2 * 8 + e] += (float)ch[e];
      }
    }
    // write combined RAW (unnormalized) back into accb[qg2][rn][c0..c0+15]
#pragma unroll
    for (int h2 = 0; h2 < 2; ++h2) {
      bf16x8 sv;
#pragma unroll
      for (int e = 0; e < 8; ++e) sv[e] = (bf16_t)o[h2 * 8 + e];
      *(bf16x8*)&accb[qg2][rn][c0 + h2 * 8] = sv;
    }
  }
  __syncthreads();

  // ---- fused output projection: out = gamma*(Wo @ attn + bo) + x ----
  // out is stream-once -> NT store (no L2 allocate); x load stays cached.
  {
    const int obk = w >> 1, nh = w & 1;
    const int o0 = obk * 32;
    f32x16 oc;
#pragma unroll
    for (int i = 0; i < 16; ++i) oc[i] = 0.f;
#pragma unroll
    for (int kk = 0; kk < 8; ++kk) {
      bf16x8 wof = *(const bf16x8*)(Wob + (size_t)(o0 + l31) * 128 + kk * 16 + 8 * hi);
      bf16x8 cf = *(const bf16x8*)&accb[nh][l31][kk * 16 + 8 * hi];
      oc = MFMA32(wof, cf, oc);  // D[o][n], n = l31
    }
    const float g = gammap[0];
    const float iv = linv[nh * 32 + l31];
    const int ng = qb * 64 + nh * 32 + l31;
#pragma unroll
    for (int r = 0; r < 16; ++r) {
      int o_ = o0 + (r & 3) + 8 * (r >> 2) + 4 * hi;
      size_t off = ((size_t)(b * 128 + o_)) * 4096 + ng;
      __builtin_nontemporal_store(g * (oc[r] * iv + bo[o_]) + x[off], &out[off]);
    }
  }
}

extern "C" void kernel_launch(void* const* d_in, const int* in_sizes, int n_in,
                              void* d_out, int out_size, void* d_ws, size_t ws_size,
                              hipStream_t stream) {
  const float* x  = (const float*)d_in[0];
  const float* Wq = (const float*)d_in[1];
  const float* bq = (const float*)d_in[2];
  const float* Wk = (const float*)d_in[3];
  const float* bk = (const float*)d_in[4];
  const float* Wv = (const float*)d_in[5];
  const float* bv = (const float*)d_in[6];
  const float* Wo = (const float*)d_in[7];
  const float* bo = (const float*)d_in[8];
  const float* gm = (const float*)d_in[9];
  float* out = (float*)d_out;

  char* ws = (char*)d_ws;
  bf16_t* q   = (bf16_t*)(ws);                        // 1 MB [B][N][16]
  bf16_t* kT  = (bf16_t*)(ws + (size_t)(1 << 20));    // 1 MB [B][N][16]
  char*   vf  = (char*)  (ws + (size_t)(2 << 20));    // 4 MB fp8 K=64-tiled V (split-plane)
  bf16_t* Wob = (bf16_t*)(ws + (size_t)(6 << 20));    // 32 KB Wo bf16

  k_qkv<<<dim3(64, 8), 256, 0, stream>>>(x, Wq, bq, Wk, bk, Wv, bv, Wo, q, kT, vf, Wob);
  k_attn<<<512, 512, 0, stream>>>(q, kT, vf, Wob, bo, gm, x, out);
}